// Round 8
// baseline (25.470 us; speedup 1.0000x reference)
//
#include <hip/hip_runtime.h>

#define H 2048
#define CH 19
#define SENT 0xFFFFFFFFu  // -NaN bits: sigm*tanh can never produce this

typedef float f32x4 __attribute__((ext_vector_type(4)));

__device__ __forceinline__ float wred(float s) {
    #pragma unroll
    for (int off = 32; off; off >>= 1) s += __shfl_down(s, off, 64);
    return s;
}

__device__ __forceinline__ float sigm(float v) { return 1.f / (1.f + expf(-v)); }

// Dual-row pipelined dot: x cached once in 32 VGPRs; BOTH weight rows' 8-deep
// nontemporal load sets issued before any FMA, so row B's HBM service hides
// under row A's FMA chain + reduce. 96 VGPR of buffers.
__device__ __forceinline__ void dot2_nt(const float* __restrict__ rowA,
                                        const float* __restrict__ rowB,
                                        const float* __restrict__ xp, int lane,
                                        float& sA, float& sB) {
    const f32x4* a = (const f32x4*)rowA;
    const f32x4* b = (const f32x4*)rowB;
    const f32x4* x = (const f32x4*)xp;
    f32x4 xr[8], wa[8], wb[8];
    #pragma unroll
    for (int j = 0; j < 8; ++j) xr[j] = x[lane + j * 64];
    #pragma unroll
    for (int j = 0; j < 8; ++j) wa[j] = __builtin_nontemporal_load(&a[lane + j * 64]);
    #pragma unroll
    for (int j = 0; j < 8; ++j) wb[j] = __builtin_nontemporal_load(&b[lane + j * 64]);
    float s0 = 0.f, s1 = 0.f;
    #pragma unroll
    for (int j = 0; j < 8; ++j)
        s0 += wa[j].x * xr[j].x + wa[j].y * xr[j].y + wa[j].z * xr[j].z + wa[j].w * xr[j].w;
    #pragma unroll
    for (int j = 0; j < 8; ++j)
        s1 += wb[j].x * xr[j].x + wb[j].y * xr[j].y + wb[j].z * xr[j].z + wb[j].w * xr[j].w;
    sA = s0; sB = s1;
}

// Zero initial state => w_hh dead, f-gate dead. Block b owns units {2b, 2b+1};
// wave w streams gate-w rows for both units. Also re-arms h1 sentinel slots
// (graph edge orders this before the layer-1 kernel).
__global__ __launch_bounds__(192) void layer0_kernel(
    const float* __restrict__ w_ih, const float* __restrict__ b_ih,
    const float* __restrict__ b_hh,
    const float* __restrict__ emb, const int* __restrict__ idxp,
    float* __restrict__ h_out, unsigned* __restrict__ h1_slots)
{
    const int b    = blockIdx.x;
    const int wave = threadIdx.x >> 6;
    const int lane = threadIdx.x & 63;
    if (threadIdx.x < 2) h1_slots[2 * b + threadIdx.x] = SENT;

    const int off = (wave == 0) ? 0 : (wave == 1 ? 2 * H : 3 * H);
    const int rA  = off + 2 * b;
    const int rB  = rA + 1;

    const float* x = emb + (size_t)idxp[0] * H;
    const float bsA = b_ih[rA] + b_hh[rA];
    const float bsB = b_ih[rB] + b_hh[rB];

    float sA, sB;
    dot2_nt(w_ih + (size_t)rA * H, w_ih + (size_t)rB * H, x, lane, sA, sB);
    sA = wred(sA); sB = wred(sB);

    __shared__ float g[3][2];
    if (lane == 0) { g[wave][0] = sA + bsA; g[wave][1] = sB + bsB; }
    __syncthreads();
    if (threadIdx.x < 2) {
        const int q = threadIdx.x;
        float si = sigm(g[0][q]);
        float so = sigm(g[2][q]);
        h_out[2 * b + q] = so * tanhf(si * tanhf(g[1][q]));
    }
}

// Layer 1 + fused logits (R7-proven): writer blocks publish h1 via relaxed
// agent-scope stores to distinct slots; 19 reader blocks poll and FMA.
__global__ __launch_bounds__(192) void layer1_logits_kernel(
    const float* __restrict__ w_ih, const float* __restrict__ b_ih,
    const float* __restrict__ b_hh,
    const float* __restrict__ h_in,
    const float* __restrict__ wc, const float* __restrict__ bc,
    const int* __restrict__ taskp,
    unsigned* __restrict__ h1_slots, float* __restrict__ out)
{
    if (blockIdx.x < H / 2) {
        const int b    = blockIdx.x;
        const int wave = threadIdx.x >> 6;
        const int lane = threadIdx.x & 63;
        const int off  = (wave == 0) ? 0 : (wave == 1 ? 2 * H : 3 * H);
        const int rA   = off + 2 * b;
        const int rB   = rA + 1;

        const float bsA = b_ih[rA] + b_hh[rA];
        const float bsB = b_ih[rB] + b_hh[rB];

        float sA, sB;
        dot2_nt(w_ih + (size_t)rA * H, w_ih + (size_t)rB * H, h_in, lane, sA, sB);
        sA = wred(sA); sB = wred(sB);

        __shared__ float g[3][2];
        if (lane == 0) { g[wave][0] = sA + bsA; g[wave][1] = sB + bsB; }
        __syncthreads();
        if (threadIdx.x < 2) {
            const int q = threadIdx.x;
            float si = sigm(g[0][q]);
            float so = sigm(g[2][q]);
            float h1 = so * tanhf(si * tanhf(g[1][q]));
            __hip_atomic_store(&h1_slots[2 * b + q], __float_as_uint(h1),
                               __ATOMIC_RELAXED, __HIP_MEMORY_SCOPE_AGENT);
        }
    } else {
        const int r = blockIdx.x - H / 2;
        const int t = threadIdx.x;
        const int task = taskp[0];
        const float* wrow = wc + (size_t)r * H;

        float wcr[11];
        #pragma unroll
        for (int k = 0; k < 11; ++k) {
            int u = t + k * 192;
            wcr[k] = (u < H) ? wrow[u] : 0.f;
        }

        float s = 0.f;
        #pragma unroll
        for (int k = 0; k < 11; ++k) {
            int u = t + k * 192;
            if (u < H) {
                unsigned v;
                for (;;) {
                    v = __hip_atomic_load(&h1_slots[u], __ATOMIC_RELAXED,
                                          __HIP_MEMORY_SCOPE_AGENT);
                    if (v != SENT) break;
                    __builtin_amdgcn_s_sleep(1);
                }
                s += wcr[k] * __uint_as_float(v);
            }
        }
        s = wred(s);

        __shared__ float p[3];
        if ((t & 63) == 0) p[t >> 6] = s;
        __syncthreads();
        if (t == 0) {
            float v = p[0] + p[1] + p[2] + bc[r];
            out[r] = (r < 1 + task) ? v : -1e9f;
        }
    }
}

extern "C" void kernel_launch(void* const* d_in, const int* in_sizes, int n_in,
                              void* d_out, int out_size, void* d_ws, size_t ws_size,
                              hipStream_t stream) {
    const int*   idx  = (const int*)d_in[0];
    const int*   task = (const int*)d_in[1];
    const float* emb  = (const float*)d_in[2];
    const float* w0   = (const float*)d_in[3];
    // d_in[4] = w_hh_0: dead (h == 0)
    const float* bi0  = (const float*)d_in[5];
    const float* bh0  = (const float*)d_in[6];
    const float* w1   = (const float*)d_in[7];
    // d_in[8] = w_hh_1: dead
    const float* bi1  = (const float*)d_in[9];
    const float* bh1  = (const float*)d_in[10];
    const float* wc   = (const float*)d_in[11];
    const float* bc   = (const float*)d_in[12];
    float* out = (float*)d_out;
    float* ws  = (float*)d_ws;

    float*    h0       = ws;                   // [H]
    unsigned* h1_slots = (unsigned*)(ws + H);  // [H]

    layer0_kernel<<<H / 2, 192, 0, stream>>>(w0, bi0, bh0, emb, idx, h0, h1_slots);
    layer1_logits_kernel<<<H / 2 + CH, 192, 0, stream>>>(w1, bi1, bh1, h0, wc, bc, task,
                                                         h1_slots, out);
}

// Round 9
// 25.054 us; speedup vs baseline: 1.0166x; 1.0166x over previous
//
#include <hip/hip_runtime.h>

#define H  2048
#define CH 19
#define NB 512                 // writer blocks (4 units each)
#define SENT 0xFFFFFFFFu       // -NaN bits; sigm*tanh can never produce this

typedef float f32x4 __attribute__((ext_vector_type(4)));

__device__ __forceinline__ float wred(float s) {
    #pragma unroll
    for (int off = 32; off; off >>= 1) s += __shfl_down(s, off, 64);
    return s;
}

__device__ __forceinline__ float sigm(float v) { return 1.f / (1.f + expf(-v)); }

// dot of one weight row (nontemporal, read-once) against an x already in registers
__device__ __forceinline__ float dot_nt_x(const float* __restrict__ rowp,
                                          const f32x4* __restrict__ xr, int lane) {
    const f32x4* row = (const f32x4*)rowp;
    f32x4 w[8];
    #pragma unroll
    for (int j = 0; j < 8; ++j) w[j] = __builtin_nontemporal_load(&row[lane + j * 64]);
    float s = 0.f;
    #pragma unroll
    for (int j = 0; j < 8; ++j)
        s += w[j].x * xr[j].x + w[j].y * xr[j].y + w[j].z * xr[j].z + w[j].w * xr[j].w;
    return s;
}

// poll a float4 group of 4 independently-published dwords until none is SENT
__device__ __forceinline__ f32x4 poll4(const unsigned* __restrict__ p) {
    unsigned a, b, c, d;
    for (;;) {
        a = __hip_atomic_load(p + 0, __ATOMIC_RELAXED, __HIP_MEMORY_SCOPE_AGENT);
        b = __hip_atomic_load(p + 1, __ATOMIC_RELAXED, __HIP_MEMORY_SCOPE_AGENT);
        c = __hip_atomic_load(p + 2, __ATOMIC_RELAXED, __HIP_MEMORY_SCOPE_AGENT);
        d = __hip_atomic_load(p + 3, __ATOMIC_RELAXED, __HIP_MEMORY_SCOPE_AGENT);
        if (a != SENT && b != SENT && c != SENT && d != SENT) break;
        __builtin_amdgcn_s_sleep(1);
    }
    f32x4 r;
    r.x = __uint_as_float(a); r.y = __uint_as_float(b);
    r.z = __uint_as_float(c); r.w = __uint_as_float(d);
    return r;
}

// Single fused kernel. Zero initial state => w_hh dead, f-gate dead.
// Blocks 0..511 (writers): wave w owns unit u=4b+w. Layer-0: 3 gate-row dots
//   against x (cached in regs), publish h0[u]. Layer-1: issue gate-i weight
//   loads FIRST (independent of h0 -> keeps HBM saturated across the dep),
//   poll h0 float4-wise, 3 dots, publish h1[u].
// Blocks 512..530 (logit pollers): prefetch wc row, poll h1, masked write.
// No fences, no shared-address atomics, no grid.sync (R3/R4 lessons).
__global__ __launch_bounds__(256) void fused_all(
    const int* __restrict__ idxp, const int* __restrict__ taskp,
    const float* __restrict__ emb,
    const float* __restrict__ w0, const float* __restrict__ bi0, const float* __restrict__ bh0,
    const float* __restrict__ w1, const float* __restrict__ bi1, const float* __restrict__ bh1,
    const float* __restrict__ wc, const float* __restrict__ bc,
    unsigned* __restrict__ h0q, unsigned* __restrict__ h1q,
    float* __restrict__ out)
{
    const int tid  = threadIdx.x;
    const int wv   = tid >> 6;
    const int lane = tid & 63;

    if (blockIdx.x < NB) {
        const int u = 4 * blockIdx.x + wv;

        // ---- layer 0 ----
        const f32x4* x4 = (const f32x4*)(emb + (size_t)idxp[0] * H);
        f32x4 xr[8];
        #pragma unroll
        for (int j = 0; j < 8; ++j) xr[j] = x4[lane + j * 64];

        float ai = dot_nt_x(w0 + (size_t)u * H,           xr, lane);
        float ag = dot_nt_x(w0 + (size_t)(2 * H + u) * H, xr, lane);
        float ao = dot_nt_x(w0 + (size_t)(3 * H + u) * H, xr, lane);
        ai = wred(ai); ag = wred(ag); ao = wred(ao);
        if (lane == 0) {
            float gi = ai + bi0[u]         + bh0[u];
            float gg = ag + bi0[2 * H + u] + bh0[2 * H + u];
            float go = ao + bi0[3 * H + u] + bh0[3 * H + u];
            float h0 = sigm(go) * tanhf(sigm(gi) * tanhf(gg));
            __hip_atomic_store(&h0q[u], __float_as_uint(h0),
                               __ATOMIC_RELAXED, __HIP_MEMORY_SCOPE_AGENT);
        }

        // ---- layer 1: issue gate-i weight loads BEFORE polling h0 ----
        const f32x4* r1 = (const f32x4*)(w1 + (size_t)u * H);
        f32x4 wb[8];
        #pragma unroll
        for (int j = 0; j < 8; ++j) wb[j] = __builtin_nontemporal_load(&r1[lane + j * 64]);

        f32x4 hr[8];
        #pragma unroll
        for (int j = 0; j < 8; ++j) hr[j] = poll4(&h0q[4 * (lane + j * 64)]);

        float bi_ = 0.f;
        #pragma unroll
        for (int j = 0; j < 8; ++j)
            bi_ += wb[j].x * hr[j].x + wb[j].y * hr[j].y + wb[j].z * hr[j].z + wb[j].w * hr[j].w;
        float bg_ = dot_nt_x(w1 + (size_t)(2 * H + u) * H, hr, lane);
        float bo_ = dot_nt_x(w1 + (size_t)(3 * H + u) * H, hr, lane);
        bi_ = wred(bi_); bg_ = wred(bg_); bo_ = wred(bo_);
        if (lane == 0) {
            float gi = bi_ + bi1[u]         + bh1[u];
            float gg = bg_ + bi1[2 * H + u] + bh1[2 * H + u];
            float go = bo_ + bi1[3 * H + u] + bh1[3 * H + u];
            float h1 = sigm(go) * tanhf(sigm(gi) * tanhf(gg));
            __hip_atomic_store(&h1q[u], __float_as_uint(h1),
                               __ATOMIC_RELAXED, __HIP_MEMORY_SCOPE_AGENT);
        }
    } else {
        // ---- logits: one block per row, 256 threads, 2 float4 groups each ----
        const int r = blockIdx.x - NB;
        const int task = taskp[0];
        const f32x4* wr = (const f32x4*)(wc + (size_t)r * H);
        f32x4 wa = wr[tid];
        f32x4 wbv = wr[tid + 256];

        f32x4 ha = poll4(&h1q[4 * tid]);
        f32x4 hb = poll4(&h1q[4 * (tid + 256)]);

        float s = wa.x * ha.x + wa.y * ha.y + wa.z * ha.z + wa.w * ha.w
                + wbv.x * hb.x + wbv.y * hb.y + wbv.z * hb.z + wbv.w * hb.w;
        s = wred(s);

        __shared__ float p[4];
        if (lane == 0) p[wv] = s;
        __syncthreads();
        if (tid == 0) {
            float v = p[0] + p[1] + p[2] + p[3] + bc[r];
            out[r] = (r < 1 + task) ? v : -1e9f;
        }
    }
}

// ---------------- fallback: proven R6 3-kernel path ----------------
__device__ __forceinline__ float dot_row_nt(const float* __restrict__ rowp,
                                            const float* __restrict__ xp, int lane) {
    const f32x4* x = (const f32x4*)xp;
    f32x4 xr[8];
    #pragma unroll
    for (int j = 0; j < 8; ++j) xr[j] = x[lane + j * 64];
    return dot_nt_x(rowp, xr, lane);
}

__global__ __launch_bounds__(192) void lstm_layer_kernel(
    const float* __restrict__ w_ih, const float* __restrict__ b_ih,
    const float* __restrict__ b_hh,
    const float* __restrict__ x_base, const int* __restrict__ idx_ptr,
    float* __restrict__ h_out)
{
    const int unit = blockIdx.x;
    const int wave = threadIdx.x >> 6;
    const int lane = threadIdx.x & 63;
    const int row  = (wave == 0) ? unit : (wave == 1 ? 2 * H + unit : 3 * H + unit);
    const float* x = x_base + (idx_ptr ? (size_t)idx_ptr[0] * H : 0);
    const float bsum = b_ih[row] + b_hh[row];
    float sum = wred(dot_row_nt(w_ih + (size_t)row * H, x, lane));
    __shared__ float g[3];
    if (lane == 0) g[wave] = sum + bsum;
    __syncthreads();
    if (threadIdx.x == 0) {
        float si = sigm(g[0]);
        float so = sigm(g[2]);
        h_out[unit] = so * tanhf(si * tanhf(g[1]));
    }
}

__global__ __launch_bounds__(64) void logits_kernel(
    const float* __restrict__ wc, const float* __restrict__ bc,
    const float* __restrict__ h, const int* __restrict__ taskp,
    float* __restrict__ out)
{
    const int r = blockIdx.x;
    const int lane = threadIdx.x;
    const int task = taskp[0];
    float s = wred(dot_row_nt(wc + (size_t)r * H, h, lane));
    if (lane == 0)
        out[r] = (r < 1 + task) ? (s + bc[r]) : -1e9f;
}

extern "C" void kernel_launch(void* const* d_in, const int* in_sizes, int n_in,
                              void* d_out, int out_size, void* d_ws, size_t ws_size,
                              hipStream_t stream) {
    const int*   idx  = (const int*)d_in[0];
    const int*   task = (const int*)d_in[1];
    const float* emb  = (const float*)d_in[2];
    const float* w0   = (const float*)d_in[3];
    // d_in[4] = w_hh_0: dead (h == 0)
    const float* bi0  = (const float*)d_in[5];
    const float* bh0  = (const float*)d_in[6];
    const float* w1   = (const float*)d_in[7];
    // d_in[8] = w_hh_1: dead
    const float* bi1  = (const float*)d_in[9];
    const float* bh1  = (const float*)d_in[10];
    const float* wc   = (const float*)d_in[11];
    const float* bc   = (const float*)d_in[12];
    float* out = (float*)d_out;

    unsigned* h0q = (unsigned*)d_ws;        // [H] dwords
    unsigned* h1q = h0q + H;                // [H] dwords

    int dev = 0;
    (void)hipGetDevice(&dev);
    int numCU = 0;
    (void)hipDeviceGetAttribute(&numCU, hipDeviceAttributeMultiprocessorCount, dev);
    int occ = 0;
    hipError_t oe = hipOccupancyMaxActiveBlocksPerMultiprocessor(&occ, fused_all, 256, 0);

    if (oe == hipSuccess && numCU > 0 && occ * numCU >= NB + CH) {
        // re-arm sentinels every call (replay-deterministic), then one fused dispatch
        hipMemsetAsync(h0q, 0xFF, 2 * H * sizeof(unsigned), stream);
        void* args[] = {(void*)&idx, (void*)&task, (void*)&emb,
                        (void*)&w0, (void*)&bi0, (void*)&bh0,
                        (void*)&w1, (void*)&bi1, (void*)&bh1,
                        (void*)&wc, (void*)&bc,
                        (void*)&h0q, (void*)&h1q, (void*)&out};
        hipError_t le = hipLaunchCooperativeKernel(fused_all, dim3(NB + CH),
                                                   dim3(256), args, 0, stream);
        if (le == hipSuccess) return;
    }

    // deterministic fallback: proven R6 3-kernel path
    float* h0 = (float*)d_ws;
    float* h1 = h0 + H;
    lstm_layer_kernel<<<H, 192, 0, stream>>>(w0, bi0, bh0, emb, idx, h0);
    lstm_layer_kernel<<<H, 192, 0, stream>>>(w1, bi1, bh1, h0, nullptr, h1);
    logits_kernel<<<CH, 64, 0, stream>>>(wc, bc, h1, task, out);
}

// Round 10
// 24.919 us; speedup vs baseline: 1.0221x; 1.0054x over previous
//
#include <hip/hip_runtime.h>

#define H 2048
#define CH 19
#define SENT 0xFFFFFFFFu  // -NaN bits: sigm*tanh can never produce this

typedef float f32x4 __attribute__((ext_vector_type(4)));

__device__ __forceinline__ float wred(float s) {
    #pragma unroll
    for (int off = 32; off; off >>= 1) s += __shfl_down(s, off, 64);
    return s;
}

__device__ __forceinline__ float sigm(float v) { return 1.f / (1.f + expf(-v)); }

// Weight row streamed from global (nontemporal, read-once) against x in LDS.
// x reads go over the LDS pipe (lgkm), freeing the entire VMEM/L1 path for
// the weight stream -> halves per-CU vector-memory traffic & instructions.
__device__ __forceinline__ float dot_nt_lds(const float* __restrict__ rowp,
                                            const float* __restrict__ xs, int lane) {
    const f32x4* row = (const f32x4*)rowp;
    const f32x4* xl  = (const f32x4*)xs;
    f32x4 w[8];
    #pragma unroll
    for (int j = 0; j < 8; ++j) w[j] = __builtin_nontemporal_load(&row[lane + j * 64]);
    float s = 0.f;
    #pragma unroll
    for (int j = 0; j < 8; ++j) {
        f32x4 xv = xl[lane + j * 64];   // ds_read_b128
        s += w[j].x * xv.x + w[j].y * xv.y + w[j].z * xv.z + w[j].w * xv.w;
    }
    return s;
}

// cooperative 8 KB stage: 192 threads x float4 (512 float4 total)
__device__ __forceinline__ void stage_x(float* __restrict__ xs,
                                        const float* __restrict__ xg, int tid) {
    const f32x4* src = (const f32x4*)xg;
    f32x4* dst = (f32x4*)xs;
    #pragma unroll
    for (int k = 0; k < 3; ++k) {
        int i = tid + k * 192;
        if (i < H / 4) dst[i] = src[i];
    }
    __syncthreads();
}

// Zero initial state => w_hh dead, f-gate dead.
// One block (3 waves) per unit: wave0 -> gate i, wave1 -> g, wave2 -> o.
// Also re-arms the h1 sentinel slots (graph edge orders this before layer 1).
__global__ __launch_bounds__(192) void layer0_kernel(
    const float* __restrict__ w_ih, const float* __restrict__ b_ih,
    const float* __restrict__ b_hh,
    const float* __restrict__ emb, const int* __restrict__ idxp,
    float* __restrict__ h_out, unsigned* __restrict__ h1_slots)
{
    __shared__ float xs[H];
    const int unit = blockIdx.x;
    const int wave = threadIdx.x >> 6;
    const int lane = threadIdx.x & 63;
    if (threadIdx.x == 0) h1_slots[unit] = SENT;

    stage_x(xs, emb + (size_t)idxp[0] * H, threadIdx.x);

    const int row  = (wave == 0) ? unit : (wave == 1 ? 2 * H + unit : 3 * H + unit);
    const float bsum = b_ih[row] + b_hh[row];
    float sum = wred(dot_nt_lds(w_ih + (size_t)row * H, xs, lane));

    __shared__ float g[3];
    if (lane == 0) g[wave] = sum + bsum;
    __syncthreads();
    if (threadIdx.x == 0) {
        float si = sigm(g[0]);
        float so = sigm(g[2]);
        h_out[unit] = so * tanhf(si * tanhf(g[1]));
    }
}

// Layer 1 + fused logits (R7-proven): writer blocks publish h1 via relaxed
// agent-scope stores to distinct slots; 19 reader blocks poll and FMA.
__global__ __launch_bounds__(192) void layer1_logits_kernel(
    const float* __restrict__ w_ih, const float* __restrict__ b_ih,
    const float* __restrict__ b_hh,
    const float* __restrict__ h_in,
    const float* __restrict__ wc, const float* __restrict__ bc,
    const int* __restrict__ taskp,
    unsigned* __restrict__ h1_slots, float* __restrict__ out)
{
    if (blockIdx.x < H) {
        __shared__ float xs[H];
        const int unit = blockIdx.x;
        const int wave = threadIdx.x >> 6;
        const int lane = threadIdx.x & 63;

        stage_x(xs, h_in, threadIdx.x);

        const int row  = (wave == 0) ? unit : (wave == 1 ? 2 * H + unit : 3 * H + unit);
        const float bsum = b_ih[row] + b_hh[row];
        float sum = wred(dot_nt_lds(w_ih + (size_t)row * H, xs, lane));

        __shared__ float g[3];
        if (lane == 0) g[wave] = sum + bsum;
        __syncthreads();
        if (threadIdx.x == 0) {
            float si = sigm(g[0]);
            float so = sigm(g[2]);
            float h1 = so * tanhf(si * tanhf(g[1]));
            __hip_atomic_store(&h1_slots[unit], __float_as_uint(h1),
                               __ATOMIC_RELAXED, __HIP_MEMORY_SCOPE_AGENT);
        }
    } else {
        const int r = blockIdx.x - H;
        const int t = threadIdx.x;
        const int task = taskp[0];
        const float* wrow = wc + (size_t)r * H;

        float wcr[11];
        #pragma unroll
        for (int k = 0; k < 11; ++k) {
            int u = t + k * 192;
            wcr[k] = (u < H) ? wrow[u] : 0.f;
        }

        float s = 0.f;
        #pragma unroll
        for (int k = 0; k < 11; ++k) {
            int u = t + k * 192;
            if (u < H) {
                unsigned v;
                for (;;) {
                    v = __hip_atomic_load(&h1_slots[u], __ATOMIC_RELAXED,
                                          __HIP_MEMORY_SCOPE_AGENT);
                    if (v != SENT) break;
                    __builtin_amdgcn_s_sleep(1);
                }
                s += wcr[k] * __uint_as_float(v);
            }
        }
        s = wred(s);

        __shared__ float p[3];
        if ((t & 63) == 0) p[t >> 6] = s;
        __syncthreads();
        if (t == 0) {
            float v = p[0] + p[1] + p[2] + bc[r];
            out[r] = (r < 1 + task) ? v : -1e9f;
        }
    }
}

extern "C" void kernel_launch(void* const* d_in, const int* in_sizes, int n_in,
                              void* d_out, int out_size, void* d_ws, size_t ws_size,
                              hipStream_t stream) {
    const int*   idx  = (const int*)d_in[0];
    const int*   task = (const int*)d_in[1];
    const float* emb  = (const float*)d_in[2];
    const float* w0   = (const float*)d_in[3];
    // d_in[4] = w_hh_0: dead (h == 0)
    const float* bi0  = (const float*)d_in[5];
    const float* bh0  = (const float*)d_in[6];
    const float* w1   = (const float*)d_in[7];
    // d_in[8] = w_hh_1: dead
    const float* bi1  = (const float*)d_in[9];
    const float* bh1  = (const float*)d_in[10];
    const float* wc   = (const float*)d_in[11];
    const float* bc   = (const float*)d_in[12];
    float* out = (float*)d_out;
    float* ws  = (float*)d_ws;

    float*    h0       = ws;                   // [H]
    unsigned* h1_slots = (unsigned*)(ws + H);  // [H]

    layer0_kernel<<<H, 192, 0, stream>>>(w0, bi0, bh0, emb, idx, h0, h1_slots);
    layer1_logits_kernel<<<H + CH, 192, 0, stream>>>(w1, bi1, bh1, h0, wc, bc, task,
                                                     h1_slots, out);
}